// Round 3
// baseline (139.533 us; speedup 1.0000x reference)
//
#include <hip/hip_runtime.h>
#include <stdint.h>

typedef __bf16 bf16x8 __attribute__((ext_vector_type(8)));
typedef short  short4v __attribute__((ext_vector_type(4)));   // 4 x bf16 bits
typedef float  floatx4 __attribute__((ext_vector_type(4)));
typedef uint32_t u32x4 __attribute__((ext_vector_type(4)));

#define DI __device__ __forceinline__

// single float -> bf16 bits (compiler-native conversion, RNE)
DI uint16_t bf1(float a) {
    union { __bf16 h; uint16_t u; } r; r.h = (__bf16)a; return r.u;
}

// ---------------------------------------------------------------------------
// Kernel 1: projections via MFMA. r9: all bf16 packing via compiler casts
// (native cvt ops; no inline asm, no manual RNE emulation).
// ---------------------------------------------------------------------------
__global__ __launch_bounds__(256) void proj_kernel(
    const float* __restrict__ x,
    const float* __restrict__ tw, const float* __restrict__ tb,
    const float* __restrict__ pw, const float* __restrict__ pb,
    const float* __restrict__ gw, const float* __restrict__ gb,
    uint16_t* __restrict__ th, uint16_t* __restrict__ phT,
    uint16_t* __restrict__ vP)
{
    __shared__ uint16_t ldsg[32 * 68];     // g-output bounce, pad 68 (8B-align ok)
    int nt = blockIdx.x & 63, blk = blockIdx.x >> 6;
    int tid = threadIdx.x, wid = tid >> 6, lane = tid & 63;
    int quad = lane >> 4, low = lane & 15;

    int b = blk & 1, q = blk >> 1, qh = q >> 1, qw = q & 1;
    int pixA = wid * 16 + low;             // pixel within 64-tile (A-row m=low)
    const float* xg = x + (size_t)b * 1048576 +
                      (size_t)(qh * 64 + nt) * 128 + qw * 64 + pixA;

    // A-frags: A0 = ch 0..31, A1 = ch 32..63;  A[m=low][k=quad*8+j]
    float a0[8], a1[8];
#pragma unroll
    for (int j = 0; j < 8; ++j) {
        a0[j] = xg[(size_t)(quad * 8 + j) * 16384];
        a1[j] = xg[(size_t)(32 + quad * 8 + j) * 16384];
    }
    bf16x8 A0, A1;
#pragma unroll
    for (int j = 0; j < 8; ++j) {
        A0[j] = (__bf16)a0[j];
        A1[j] = (__bf16)a1[j];
    }

    // one 16-o output tile: D[m=pixel][n=o0+low] = sum_c x*w + bias
    auto dotile = [&](const float* W, const float* Bv, int o0) -> floatx4 {
        floatx4 acc;
        float bias = Bv[o0 + low];
#pragma unroll
        for (int r = 0; r < 4; ++r) acc[r] = bias;
        const float* wr = W + (o0 + low) * 64 + quad * 8;   // 32B-aligned
        floatx4 w0a = *(const floatx4*)(wr);
        floatx4 w0b = *(const floatx4*)(wr + 4);
        floatx4 w1a = *(const floatx4*)(wr + 32);
        floatx4 w1b = *(const floatx4*)(wr + 36);
        bf16x8 B0, B1;
#pragma unroll
        for (int j = 0; j < 4; ++j) {
            B0[j]     = (__bf16)w0a[j];
            B0[j + 4] = (__bf16)w0b[j];
            B1[j]     = (__bf16)w1a[j];
            B1[j + 4] = (__bf16)w1b[j];
        }
        acc = __builtin_amdgcn_mfma_f32_16x16x32_bf16(A0, B0, acc, 0, 0, 0);
        acc = __builtin_amdgcn_mfma_f32_16x16x32_bf16(A1, B1, acc, 0, 0, 0);
        return acc;
    };

    // D rows: pixel = nt*64 + wid*16 + quad*4 + r; cols: o = o0 + low
    size_t thbase = ((size_t)blk * 4096 + nt * 64 + wid * 16 + quad * 4) * 32;

    floatx4 t0 = dotile(tw, tb, 0), t1 = dotile(tw, tb, 16);
#pragma unroll
    for (int r = 0; r < 4; ++r) {
        th[thbase + r * 32 + low]      = bf1(t0[r] * 1.44269504088896f);
        th[thbase + r * 32 + 16 + low] = bf1(t1[r] * 1.44269504088896f);
    }
    floatx4 p0 = dotile(pw, pb, 0), p1 = dotile(pw, pb, 16);
#pragma unroll
    for (int r = 0; r < 4; ++r) {
        phT[thbase + r * 32 + low]      = bf1(p0[r]);
        phT[thbase + r * 32 + 16 + low] = bf1(p1[r]);
    }
    floatx4 g0 = dotile(gw, gb, 0), g1 = dotile(gw, gb, 16);
#pragma unroll
    for (int r = 0; r < 4; ++r) {
        ldsg[(low)      * 68 + wid * 16 + quad * 4 + r] = bf1(g0[r]);
        ldsg[(16 + low) * 68 + wid * 16 + quad * 4 + r] = bf1(g1[r]);
    }
    __syncthreads();
    // coalesced write-out: thread -> 16B of vP [o=tid>>3][k=(tid&7)*8]
    {
        int o = tid >> 3, k = (tid & 7) * 8;
        const uint16_t* src = &ldsg[o * 68 + k];
        uint64_t lo = *(const uint64_t*)(src);       // 8B-aligned
        uint64_t hi = *(const uint64_t*)(src + 4);
        union { uint64_t q[2]; u32x4 v; } out;
        out.q[0] = lo; out.q[1] = hi;
        *(u32x4*)(vP + (size_t)blk * 131072 + nt * 2048 + tid * 8) = out.v;
    }
}

// ---------------------------------------------------------------------------
// Kernel 2: fused attention + W-projection + BN partial sums.
// r9 over r7 (split-K structure kept):
//  - bf16 packing via compiler casts (r8's inline-asm cvt_pk produced NaN)
//  - subtile-order staggered by wave parity (s ^ (wid&1)): half the waves
//    run QK-MFMA while the other half runs exp2/PV -> pipes interleave
//    instead of alternating (the r7 convoy effect)
//  - NO s_setprio this round (isolate; re-add as A/B once green)
// ---------------------------------------------------------------------------
__global__ __launch_bounds__(512, 4) void flash_kernel(
    const uint16_t* __restrict__ th, const uint16_t* __restrict__ phT,
    const uint16_t* __restrict__ vP, const float* __restrict__ w_w,
    const float* __restrict__ w_b, float* __restrict__ wy,
    float2* __restrict__ partials)
{
    __shared__ uint16_t ldsK[2][2][2][64 * 40];   // [half][buf][subtile] 40KB
    __shared__ uint16_t ldsV[2][2][2][32 * 72];   // [half][buf][subtile] 36KB
    __shared__ float sred[4][64][2];              // 2KB   (total 78KB -> 2 WG/CU)
    int blk = blockIdx.x & 7;          // XCD-clustered
    int rg  = blockIdx.x >> 3;
    int tid = threadIdx.x, wid = tid >> 6, lane = tid & 63;
    int half = wid >> 2, w4 = wid & 3;
    int ltid = tid & 255;              // thread index within half-group
    int quad = lane >> 4, low = lane & 15;
    int n0 = rg * 64 + w4 * 16;
    int sstag = wid & 1;               // subtile-order stagger

    const uint16_t* thB = th  + (size_t)blk * 131072;
    const uint16_t* kG  = phT + (size_t)blk * 131072;
    const uint16_t* vG  = vP  + (size_t)blk * 131072;

    bf16x8 qf = *(const bf16x8*)(thB + (n0 + low) * 32 + quad * 8);

    const int kWr = (ltid >> 2) * 40 + (ltid & 3) * 8;   // u16 idx, 16B aligned
    const int vWr = (ltid >> 3) * 72 + (ltid & 7) * 8;
    // half h starts at key-tile 32h: +32h*256 u32x4 units = 8192h
    const u32x4* kSrc = (const u32x4*)kG + half * 8192 + ltid;
    const u32x4* vSrc = (const u32x4*)vG + half * 8192 + ltid;

    u32x4 kr0 = kSrc[0],  kr1 = kSrc[256];
    u32x4 vr0 = vSrc[0],  vr1 = vSrc[256];
    *(u32x4*)(&ldsK[half][0][0][kWr]) = kr0;  *(u32x4*)(&ldsK[half][0][1][kWr]) = kr1;
    *(u32x4*)(&ldsV[half][0][0][vWr]) = vr0;  *(u32x4*)(&ldsV[half][0][1][vWr]) = vr1;
    __syncthreads();

    floatx4 zero = {0.f, 0.f, 0.f, 0.f};
    floatx4 oa0 = zero, oa1 = zero, os = zero;
    union { uint32_t u[2]; short4v v; } ones;
    ones.u[0] = 0x3F803F80u; ones.u[1] = 0x3F803F80u;

    for (int t = 0; t < 16; ++t) {
        int buf = t & 1;
        if (t < 15) {
            kr0 = kSrc[(2*t + 2) * 256]; kr1 = kSrc[(2*t + 3) * 256];
            vr0 = vSrc[(2*t + 2) * 256]; vr1 = vSrc[(2*t + 3) * 256];
        }
#pragma unroll
        for (int si = 0; si < 2; ++si) {
            int s = si ^ sstag;                    // wave-parity stagger
            const uint16_t* Kb = ldsK[half][buf][s];
            const uint16_t* Vb = ldsV[half][buf][s];
            bf16x8  kf[4]; short4v va[4], vb[4];
#pragma unroll
            for (int c = 0; c < 4; ++c) {
                kf[c] = *(const bf16x8*)(Kb + (c * 16 + low) * 40 + quad * 8);
                va[c] = *(const short4v*)(Vb + low * 72 + c * 16 + quad * 4);
                vb[c] = *(const short4v*)(Vb + (16 + low) * 72 + c * 16 + quad * 4);
            }
            floatx4 sa[4];
#pragma unroll
            for (int c = 0; c < 4; ++c)
                sa[c] = __builtin_amdgcn_mfma_f32_16x16x32_bf16(kf[c], qf, zero, 0, 0, 0);
            union { __bf16 h[4]; short4v v; } P[4];
#pragma unroll
            for (int c = 0; c < 4; ++c) {
                float p0 = __builtin_amdgcn_exp2f(sa[c][0]);
                float p1 = __builtin_amdgcn_exp2f(sa[c][1]);
                float p2 = __builtin_amdgcn_exp2f(sa[c][2]);
                float p3 = __builtin_amdgcn_exp2f(sa[c][3]);
                P[c].h[0] = (__bf16)p0; P[c].h[1] = (__bf16)p1;
                P[c].h[2] = (__bf16)p2; P[c].h[3] = (__bf16)p3;
            }
#pragma unroll
            for (int c = 0; c < 4; ++c) {
                oa0 = __builtin_amdgcn_mfma_f32_16x16x16bf16_1k(va[c], P[c].v, oa0, 0, 0, 0);
                oa1 = __builtin_amdgcn_mfma_f32_16x16x16bf16_1k(vb[c], P[c].v, oa1, 0, 0, 0);
                os  = __builtin_amdgcn_mfma_f32_16x16x16bf16_1k(ones.v, P[c].v, os, 0, 0, 0);
            }
        }
        if (t < 15) {
            *(u32x4*)(&ldsK[half][buf ^ 1][0][kWr]) = kr0;
            *(u32x4*)(&ldsK[half][buf ^ 1][1][kWr]) = kr1;
            *(u32x4*)(&ldsV[half][buf ^ 1][0][vWr]) = vr0;
            *(u32x4*)(&ldsV[half][buf ^ 1][1][vWr]) = vr1;
        }
        __syncthreads();
    }

    // ---- cross-half combine: exchange (oa0, oa1, os) via reused K-LDS ----
    {
        float* exM = (float*)(&ldsK[half][0][0][0]);
        int li9 = ltid * 9;
#pragma unroll
        for (int r = 0; r < 4; ++r) {
            exM[li9 + r]     = oa0[r];
            exM[li9 + 4 + r] = oa1[r];
        }
        exM[li9 + 8] = os[0];
    }
    __syncthreads();
    const float* exO = (const float*)(&ldsK[half ^ 1][0][0][0]);
    float os0 = os[0] + exO[ltid * 9 + 8];
#pragma unroll
    for (int r = 0; r < 4; ++r) {
        oa0[r] += exO[ltid * 9 + r];
        oa1[r] += exO[ltid * 9 + 4 + r];
    }

    // ---- epilogue: normalize, W-projection via MFMA, BN partials ----
    // each half does 2 of the 4 ct tiles (channels [32*half, 32*half+32))
    float rinv = 1.0f / os0;
    union { __bf16 h[4]; short4v v; } Y0, Y1;
#pragma unroll
    for (int r = 0; r < 4; ++r) {
        Y0.h[r] = (__bf16)(oa0[r] * rinv);
        Y1.h[r] = (__bf16)(oa1[r] * rinv);
    }

    float* wyB = wy + (size_t)blk * 262144;
    int n = n0 + low;
#pragma unroll
    for (int cc = 0; cc < 2; ++cc) {
        int ct = half * 2 + cc;
        floatx4 acc;
#pragma unroll
        for (int r = 0; r < 4; ++r) acc[r] = w_b[ct * 16 + quad * 4 + r];
        floatx4 w0 = *(const floatx4*)(w_w + (ct * 16 + low) * 32 + quad * 4);
        floatx4 w1 = *(const floatx4*)(w_w + (ct * 16 + low) * 32 + 16 + quad * 4);
        union { __bf16 h[4]; short4v v; } W0, W1;
#pragma unroll
        for (int r = 0; r < 4; ++r) {
            W0.h[r] = (__bf16)w0[r];
            W1.h[r] = (__bf16)w1[r];
        }
        acc = __builtin_amdgcn_mfma_f32_16x16x16bf16_1k(W0.v, Y0.v, acc, 0, 0, 0);
        acc = __builtin_amdgcn_mfma_f32_16x16x16bf16_1k(W1.v, Y1.v, acc, 0, 0, 0);
#pragma unroll
        for (int r = 0; r < 4; ++r) {
            wyB[(size_t)(ct * 16 + quad * 4 + r) * 4096 + n] = acc[r];
            float s = acc[r], ss = acc[r] * acc[r];
            s += __shfl_xor(s, 1); ss += __shfl_xor(ss, 1);
            s += __shfl_xor(s, 2); ss += __shfl_xor(ss, 2);
            s += __shfl_xor(s, 4); ss += __shfl_xor(ss, 4);
            s += __shfl_xor(s, 8); ss += __shfl_xor(ss, 8);
            if (low == 0) {
                sred[w4][ct * 16 + quad * 4 + r][0] = s;
                sred[w4][ct * 16 + quad * 4 + r][1] = ss;
            }
        }
    }
    __syncthreads();
    if (tid < 64) {
        float s  = sred[0][tid][0] + sred[1][tid][0] + sred[2][tid][0] + sred[3][tid][0];
        float ss = sred[0][tid][1] + sred[1][tid][1] + sred[2][tid][1] + sred[3][tid][1];
        // canonical (blk-major) index so stats_kernel stays unchanged
        partials[((size_t)blk * 64 + rg) * 64 + tid] = make_float2(s, ss);
    }
}

// ---------------------------------------------------------------------------
// Kernel 3: BN stats — grid 4 (q), block 256 (=4 groups x 64 c).
// ---------------------------------------------------------------------------
__global__ __launch_bounds__(256) void stats_kernel(
    const float2* __restrict__ partials, const float* __restrict__ gamma,
    const float* __restrict__ beta, float2* __restrict__ stats)
{
    int q = blockIdx.x;
    int c = threadIdx.x & 63, g = threadIdx.x >> 6;
    float S = 0.f, SS = 0.f;
    for (int w = g; w < 128; w += 4) {         // b(2) x rg(64)
        int wg = (q * 2 + (w >> 6)) * 64 + (w & 63);
        float2 p = partials[(size_t)wg * 64 + c];
        S += p.x; SS += p.y;
    }
    __shared__ float sh[2][4][64];
    sh[0][g][c] = S; sh[1][g][c] = SS;
    __syncthreads();
    if (threadIdx.x < 64) {
        int cc = threadIdx.x;
        float St  = sh[0][0][cc] + sh[0][1][cc] + sh[0][2][cc] + sh[0][3][cc];
        float SSt = sh[1][0][cc] + sh[1][1][cc] + sh[1][2][cc] + sh[1][3][cc];
        float mu  = St * (1.0f / 8192.0f);
        float var = SSt * (1.0f / 8192.0f) - mu * mu;
        float scale = gamma[cc] * rsqrtf(var + 1e-5f);
        float shift = beta[cc] - mu * scale;
        stats[q * 64 + cc] = make_float2(scale, shift);
    }
}

// ---------------------------------------------------------------------------
// Kernel 4: out = (wy * scale + shift) + x, float4-vectorized reassembly.
// ---------------------------------------------------------------------------
__global__ __launch_bounds__(256) void final_kernel(
    const float* __restrict__ wy, const float2* __restrict__ stats,
    const float* __restrict__ x, float* __restrict__ out)
{
    size_t base = ((size_t)blockIdx.x * 256 + threadIdx.x) * 4;
    int n   = (int)(base & 4095);
    int c   = (int)((base >> 12) & 63);
    int blk = (int)(base >> 18);
    int b = blk & 1, q = blk >> 1, qh = q >> 1, qw = q & 1;
    int i = n >> 6, j = n & 63;
    float2 sc = stats[q * 64 + c];
    floatx4 wv = *(const floatx4*)(wy + base);
    size_t xa = ((size_t)(b * 64 + c) * 128 + (qh * 64 + i)) * 128 + qw * 64 + j;
    floatx4 xv = *(const floatx4*)(x + xa);
    floatx4 ov;
#pragma unroll
    for (int k = 0; k < 4; ++k) ov[k] = wv[k] * sc.x + sc.y + xv[k];
    *(floatx4*)(out + xa) = ov;
}

// ---------------------------------------------------------------------------
extern "C" void kernel_launch(void* const* d_in, const int* in_sizes, int n_in,
                              void* d_out, int out_size, void* d_ws, size_t ws_size,
                              hipStream_t stream)
{
    const float* x       = (const float*)d_in[0];
    const float* g_w     = (const float*)d_in[1];
    const float* g_b     = (const float*)d_in[2];
    const float* theta_w = (const float*)d_in[3];
    const float* theta_b = (const float*)d_in[4];
    const float* phi_w   = (const float*)d_in[5];
    const float* phi_b   = (const float*)d_in[6];
    const float* w_w     = (const float*)d_in[7];
    const float* w_b     = (const float*)d_in[8];
    const float* gamma   = (const float*)d_in[9];
    const float* beta    = (const float*)d_in[10];

    char* ws = (char*)d_ws;
    uint16_t* th       = (uint16_t*)(ws);                 // 0 .. 2M
    uint16_t* phT      = (uint16_t*)(ws + (2u << 20));    // 2 .. 4M
    uint16_t* vP       = (uint16_t*)(ws + (4u << 20));    // 4 .. 6M
    float*    wy       = (float*)(ws + (6u << 20));       // 6 .. 14M
    float2*   partials = (float2*)(ws + (14u << 20));     // 256 KB
    float2*   stats    = (float2*)(ws + (14u << 20) + (1u << 18));

    proj_kernel  <<<512,  256, 0, stream>>>(x, theta_w, theta_b, phi_w, phi_b,
                                            g_w, g_b, th, phT, vP);
    flash_kernel <<<512,  512, 0, stream>>>(th, phT, vP, w_w, w_b, wy, partials);
    stats_kernel <<<4,    256, 0, stream>>>(partials, gamma, beta, stats);
    final_kernel <<<2048, 256, 0, stream>>>(wy, stats, x, (float*)d_out);
}

// Round 4
// 128.123 us; speedup vs baseline: 1.0891x; 1.0891x over previous
//
#include <hip/hip_runtime.h>
#include <stdint.h>

typedef __bf16 bf16x8 __attribute__((ext_vector_type(8)));
typedef short  short4v __attribute__((ext_vector_type(4)));   // 4 x bf16 bits
typedef float  floatx4 __attribute__((ext_vector_type(4)));
typedef uint32_t u32x4 __attribute__((ext_vector_type(4)));

#define DI __device__ __forceinline__

// single float -> bf16 bits (compiler-native conversion, RNE)
DI uint16_t bf1(float a) {
    union { __bf16 h; uint16_t u; } r; r.h = (__bf16)a; return r.u;
}

// ---------------------------------------------------------------------------
// Kernel 1: projections via MFMA (unchanged from r9).
// ---------------------------------------------------------------------------
__global__ __launch_bounds__(256) void proj_kernel(
    const float* __restrict__ x,
    const float* __restrict__ tw, const float* __restrict__ tb,
    const float* __restrict__ pw, const float* __restrict__ pb,
    const float* __restrict__ gw, const float* __restrict__ gb,
    uint16_t* __restrict__ th, uint16_t* __restrict__ phT,
    uint16_t* __restrict__ vP)
{
    __shared__ uint16_t ldsg[32 * 68];     // g-output bounce, pad 68 (8B-align ok)
    int nt = blockIdx.x & 63, blk = blockIdx.x >> 6;
    int tid = threadIdx.x, wid = tid >> 6, lane = tid & 63;
    int quad = lane >> 4, low = lane & 15;

    int b = blk & 1, q = blk >> 1, qh = q >> 1, qw = q & 1;
    int pixA = wid * 16 + low;             // pixel within 64-tile (A-row m=low)
    const float* xg = x + (size_t)b * 1048576 +
                      (size_t)(qh * 64 + nt) * 128 + qw * 64 + pixA;

    // A-frags: A0 = ch 0..31, A1 = ch 32..63;  A[m=low][k=quad*8+j]
    float a0[8], a1[8];
#pragma unroll
    for (int j = 0; j < 8; ++j) {
        a0[j] = xg[(size_t)(quad * 8 + j) * 16384];
        a1[j] = xg[(size_t)(32 + quad * 8 + j) * 16384];
    }
    bf16x8 A0, A1;
#pragma unroll
    for (int j = 0; j < 8; ++j) {
        A0[j] = (__bf16)a0[j];
        A1[j] = (__bf16)a1[j];
    }

    // one 16-o output tile: D[m=pixel][n=o0+low] = sum_c x*w + bias
    auto dotile = [&](const float* W, const float* Bv, int o0) -> floatx4 {
        floatx4 acc;
        float bias = Bv[o0 + low];
#pragma unroll
        for (int r = 0; r < 4; ++r) acc[r] = bias;
        const float* wr = W + (o0 + low) * 64 + quad * 8;   // 32B-aligned
        floatx4 w0a = *(const floatx4*)(wr);
        floatx4 w0b = *(const floatx4*)(wr + 4);
        floatx4 w1a = *(const floatx4*)(wr + 32);
        floatx4 w1b = *(const floatx4*)(wr + 36);
        bf16x8 B0, B1;
#pragma unroll
        for (int j = 0; j < 4; ++j) {
            B0[j]     = (__bf16)w0a[j];
            B0[j + 4] = (__bf16)w0b[j];
            B1[j]     = (__bf16)w1a[j];
            B1[j + 4] = (__bf16)w1b[j];
        }
        acc = __builtin_amdgcn_mfma_f32_16x16x32_bf16(A0, B0, acc, 0, 0, 0);
        acc = __builtin_amdgcn_mfma_f32_16x16x32_bf16(A1, B1, acc, 0, 0, 0);
        return acc;
    };

    // D rows: pixel = nt*64 + wid*16 + quad*4 + r; cols: o = o0 + low
    size_t thbase = ((size_t)blk * 4096 + nt * 64 + wid * 16 + quad * 4) * 32;

    floatx4 t0 = dotile(tw, tb, 0), t1 = dotile(tw, tb, 16);
#pragma unroll
    for (int r = 0; r < 4; ++r) {
        th[thbase + r * 32 + low]      = bf1(t0[r] * 1.44269504088896f);
        th[thbase + r * 32 + 16 + low] = bf1(t1[r] * 1.44269504088896f);
    }
    floatx4 p0 = dotile(pw, pb, 0), p1 = dotile(pw, pb, 16);
#pragma unroll
    for (int r = 0; r < 4; ++r) {
        phT[thbase + r * 32 + low]      = bf1(p0[r]);
        phT[thbase + r * 32 + 16 + low] = bf1(p1[r]);
    }
    floatx4 g0 = dotile(gw, gb, 0), g1 = dotile(gw, gb, 16);
#pragma unroll
    for (int r = 0; r < 4; ++r) {
        ldsg[(low)      * 68 + wid * 16 + quad * 4 + r] = bf1(g0[r]);
        ldsg[(16 + low) * 68 + wid * 16 + quad * 4 + r] = bf1(g1[r]);
    }
    __syncthreads();
    // coalesced write-out: thread -> 16B of vP [o=tid>>3][k=(tid&7)*8]
    {
        int o = tid >> 3, k = (tid & 7) * 8;
        const uint16_t* src = &ldsg[o * 68 + k];
        uint64_t lo = *(const uint64_t*)(src);       // 8B-aligned
        uint64_t hi = *(const uint64_t*)(src + 4);
        union { uint64_t q[2]; u32x4 v; } out;
        out.q[0] = lo; out.q[1] = hi;
        *(u32x4*)(vP + (size_t)blk * 131072 + nt * 2048 + tid * 8) = out.v;
    }
}

// ---------------------------------------------------------------------------
// Kernel 2: fused attention + W-projection + BN partial sums.
// r10: DUAL-QUERY waves. Each wave owns 32 queries (groups A and B); each
// staged K/V fragment is read from LDS once and feeds both groups' MFMAs.
// Per-query LDS traffic halves (LDS was the dominant pipe: ~63% busy at r9).
// grid: 256 WGs = 8 blk x 32 rg; WG = 512 thr = 8 waves (K-split-2 kept:
// waves 0-3 keys 0..2047, waves 4-7 keys 2048..4095). WG covers 128 queries.
// ---------------------------------------------------------------------------
__global__ __launch_bounds__(512, 2) void flash_kernel(
    const uint16_t* __restrict__ th, const uint16_t* __restrict__ phT,
    const uint16_t* __restrict__ vP, const float* __restrict__ w_w,
    const float* __restrict__ w_b, float* __restrict__ wy,
    float2* __restrict__ partials)
{
    __shared__ uint16_t ldsK[2][2][2][64 * 40];   // [half][buf][subtile] 40KB
    __shared__ uint16_t ldsV[2][2][2][32 * 72];   // [half][buf][subtile] 36KB
    __shared__ float sred[4][64][2];              // 2KB
    int blk = blockIdx.x & 7;          // XCD-clustered
    int rg  = blockIdx.x >> 3;         // 0..31
    int tid = threadIdx.x, wid = tid >> 6, lane = tid & 63;
    int half = wid >> 2, w4 = wid & 3;
    int ltid = tid & 255;              // thread index within half-group
    int quad = lane >> 4, low = lane & 15;
    int n0 = rg * 128 + w4 * 32;       // wave's 32-query base

    const uint16_t* thB = th  + (size_t)blk * 131072;
    const uint16_t* kG  = phT + (size_t)blk * 131072;
    const uint16_t* vG  = vP  + (size_t)blk * 131072;

    bf16x8 qfA = *(const bf16x8*)(thB + (n0 + low) * 32 + quad * 8);
    bf16x8 qfB = *(const bf16x8*)(thB + (n0 + 16 + low) * 32 + quad * 8);

    const int kWr = (ltid >> 2) * 40 + (ltid & 3) * 8;   // u16 idx, 16B aligned
    const int vWr = (ltid >> 3) * 72 + (ltid & 7) * 8;
    // half h starts at key-tile 32h: +32h*256 u32x4 units = 8192h
    const u32x4* kSrc = (const u32x4*)kG + half * 8192 + ltid;
    const u32x4* vSrc = (const u32x4*)vG + half * 8192 + ltid;

    u32x4 kr0 = kSrc[0],  kr1 = kSrc[256];
    u32x4 vr0 = vSrc[0],  vr1 = vSrc[256];
    *(u32x4*)(&ldsK[half][0][0][kWr]) = kr0;  *(u32x4*)(&ldsK[half][0][1][kWr]) = kr1;
    *(u32x4*)(&ldsV[half][0][0][vWr]) = vr0;  *(u32x4*)(&ldsV[half][0][1][vWr]) = vr1;
    __syncthreads();

    floatx4 zero = {0.f, 0.f, 0.f, 0.f};
    floatx4 oaA0 = zero, oaA1 = zero, osA = zero;
    floatx4 oaB0 = zero, oaB1 = zero, osB = zero;
    union { uint32_t u[2]; short4v v; } ones;
    ones.u[0] = 0x3F803F80u; ones.u[1] = 0x3F803F80u;

    for (int t = 0; t < 16; ++t) {
        int buf = t & 1;
        if (t < 15) {
            kr0 = kSrc[(2*t + 2) * 256]; kr1 = kSrc[(2*t + 3) * 256];
            vr0 = vSrc[(2*t + 2) * 256]; vr1 = vSrc[(2*t + 3) * 256];
        }
#pragma unroll
        for (int s = 0; s < 2; ++s) {
            const uint16_t* Kb = ldsK[half][buf][s];
            const uint16_t* Vb = ldsV[half][buf][s];
            bf16x8  kf[4]; short4v va[4], vb[4];
#pragma unroll
            for (int c = 0; c < 4; ++c) {
                kf[c] = *(const bf16x8*)(Kb + (c * 16 + low) * 40 + quad * 8);
                va[c] = *(const short4v*)(Vb + low * 72 + c * 16 + quad * 4);
                vb[c] = *(const short4v*)(Vb + (16 + low) * 72 + c * 16 + quad * 4);
            }
            floatx4 saA[4], saB[4];
#pragma unroll
            for (int c = 0; c < 4; ++c) {
                saA[c] = __builtin_amdgcn_mfma_f32_16x16x32_bf16(kf[c], qfA, zero, 0, 0, 0);
                saB[c] = __builtin_amdgcn_mfma_f32_16x16x32_bf16(kf[c], qfB, zero, 0, 0, 0);
            }
            union { __bf16 h[4]; short4v v; } PA[4], PB[4];
#pragma unroll
            for (int c = 0; c < 4; ++c) {
                PA[c].h[0] = (__bf16)__builtin_amdgcn_exp2f(saA[c][0]);
                PA[c].h[1] = (__bf16)__builtin_amdgcn_exp2f(saA[c][1]);
                PA[c].h[2] = (__bf16)__builtin_amdgcn_exp2f(saA[c][2]);
                PA[c].h[3] = (__bf16)__builtin_amdgcn_exp2f(saA[c][3]);
                PB[c].h[0] = (__bf16)__builtin_amdgcn_exp2f(saB[c][0]);
                PB[c].h[1] = (__bf16)__builtin_amdgcn_exp2f(saB[c][1]);
                PB[c].h[2] = (__bf16)__builtin_amdgcn_exp2f(saB[c][2]);
                PB[c].h[3] = (__bf16)__builtin_amdgcn_exp2f(saB[c][3]);
            }
#pragma unroll
            for (int c = 0; c < 4; ++c) {
                oaA0 = __builtin_amdgcn_mfma_f32_16x16x16bf16_1k(va[c], PA[c].v, oaA0, 0, 0, 0);
                oaB0 = __builtin_amdgcn_mfma_f32_16x16x16bf16_1k(va[c], PB[c].v, oaB0, 0, 0, 0);
                oaA1 = __builtin_amdgcn_mfma_f32_16x16x16bf16_1k(vb[c], PA[c].v, oaA1, 0, 0, 0);
                oaB1 = __builtin_amdgcn_mfma_f32_16x16x16bf16_1k(vb[c], PB[c].v, oaB1, 0, 0, 0);
                osA  = __builtin_amdgcn_mfma_f32_16x16x16bf16_1k(ones.v, PA[c].v, osA, 0, 0, 0);
                osB  = __builtin_amdgcn_mfma_f32_16x16x16bf16_1k(ones.v, PB[c].v, osB, 0, 0, 0);
            }
        }
        if (t < 15) {
            *(u32x4*)(&ldsK[half][buf ^ 1][0][kWr]) = kr0;
            *(u32x4*)(&ldsK[half][buf ^ 1][1][kWr]) = kr1;
            *(u32x4*)(&ldsV[half][buf ^ 1][0][vWr]) = vr0;
            *(u32x4*)(&ldsV[half][buf ^ 1][1][vWr]) = vr1;
        }
        __syncthreads();
    }

    // ---- cross-half combine: exchange 18 floats/thread via reused K-LDS ----
    {
        float* exM = (float*)(&ldsK[half][0][0][0]);   // 256*18*4B = 18KB < 20KB
        int li = ltid * 18;
#pragma unroll
        for (int r = 0; r < 4; ++r) {
            exM[li + r]      = oaA0[r];
            exM[li + 4 + r]  = oaA1[r];
            exM[li + 9 + r]  = oaB0[r];
            exM[li + 13 + r] = oaB1[r];
        }
        exM[li + 8]  = osA[0];
        exM[li + 17] = osB[0];
    }
    __syncthreads();
    const float* exO = (const float*)(&ldsK[half ^ 1][0][0][0]);
    float osA0 = osA[0] + exO[ltid * 18 + 8];
    float osB0 = osB[0] + exO[ltid * 18 + 17];
#pragma unroll
    for (int r = 0; r < 4; ++r) {
        oaA0[r] += exO[ltid * 18 + r];
        oaA1[r] += exO[ltid * 18 + 4 + r];
        oaB0[r] += exO[ltid * 18 + 9 + r];
        oaB1[r] += exO[ltid * 18 + 13 + r];
    }

    // ---- epilogue: normalize, W-projection via MFMA, BN partials ----
    // each half does 2 of the 4 ct tiles, for both query groups
    float rinvA = 1.0f / osA0, rinvB = 1.0f / osB0;
    union { __bf16 h[4]; short4v v; } YA0, YA1, YB0, YB1;
#pragma unroll
    for (int r = 0; r < 4; ++r) {
        YA0.h[r] = (__bf16)(oaA0[r] * rinvA);
        YA1.h[r] = (__bf16)(oaA1[r] * rinvA);
        YB0.h[r] = (__bf16)(oaB0[r] * rinvB);
        YB1.h[r] = (__bf16)(oaB1[r] * rinvB);
    }

    float* wyB = wy + (size_t)blk * 262144;
    int nA = n0 + low, nB = n0 + 16 + low;
#pragma unroll
    for (int cc = 0; cc < 2; ++cc) {
        int ct = half * 2 + cc;
        floatx4 accA, accB;
#pragma unroll
        for (int r = 0; r < 4; ++r) {
            accA[r] = w_b[ct * 16 + quad * 4 + r];
            accB[r] = accA[r];
        }
        floatx4 w0 = *(const floatx4*)(w_w + (ct * 16 + low) * 32 + quad * 4);
        floatx4 w1 = *(const floatx4*)(w_w + (ct * 16 + low) * 32 + 16 + quad * 4);
        union { __bf16 h[4]; short4v v; } W0, W1;
#pragma unroll
        for (int r = 0; r < 4; ++r) {
            W0.h[r] = (__bf16)w0[r];
            W1.h[r] = (__bf16)w1[r];
        }
        accA = __builtin_amdgcn_mfma_f32_16x16x16bf16_1k(W0.v, YA0.v, accA, 0, 0, 0);
        accA = __builtin_amdgcn_mfma_f32_16x16x16bf16_1k(W1.v, YA1.v, accA, 0, 0, 0);
        accB = __builtin_amdgcn_mfma_f32_16x16x16bf16_1k(W0.v, YB0.v, accB, 0, 0, 0);
        accB = __builtin_amdgcn_mfma_f32_16x16x16bf16_1k(W1.v, YB1.v, accB, 0, 0, 0);
#pragma unroll
        for (int r = 0; r < 4; ++r) {
            int ch = ct * 16 + quad * 4 + r;
            wyB[(size_t)ch * 4096 + nA] = accA[r];
            wyB[(size_t)ch * 4096 + nB] = accB[r];
            float s = accA[r] + accB[r];
            float ss = accA[r] * accA[r] + accB[r] * accB[r];
            s += __shfl_xor(s, 1); ss += __shfl_xor(ss, 1);
            s += __shfl_xor(s, 2); ss += __shfl_xor(ss, 2);
            s += __shfl_xor(s, 4); ss += __shfl_xor(ss, 4);
            s += __shfl_xor(s, 8); ss += __shfl_xor(ss, 8);
            if (low == 0) {
                sred[w4][ch][0] = s;
                sred[w4][ch][1] = ss;
            }
        }
    }
    __syncthreads();
    if (tid < 64) {
        float s  = sred[0][tid][0] + sred[1][tid][0] + sred[2][tid][0] + sred[3][tid][0];
        float ss = sred[0][tid][1] + sred[1][tid][1] + sred[2][tid][1] + sred[3][tid][1];
        partials[((size_t)blk * 32 + rg) * 64 + tid] = make_float2(s, ss);
    }
}

// ---------------------------------------------------------------------------
// Kernel 3: BN stats — r10: fully parallel. grid 256 = (q<<6)|c, block 64.
// Each block reduces 64 partials (2 b x 32 rg) for one (q,c) via shuffles.
// ---------------------------------------------------------------------------
__global__ __launch_bounds__(64) void stats_kernel(
    const float2* __restrict__ partials, const float* __restrict__ gamma,
    const float* __restrict__ beta, float2* __restrict__ stats)
{
    int q = blockIdx.x >> 6, c = blockIdx.x & 63;
    int t = threadIdx.x;
    int b = t >> 5, rg = t & 31;
    int blk = q * 2 + b;                        // proj/flash blk = q*2 + b
    float2 p = partials[((size_t)blk * 32 + rg) * 64 + c];
    float S = p.x, SS = p.y;
    S += __shfl_xor(S, 1);  SS += __shfl_xor(SS, 1);
    S += __shfl_xor(S, 2);  SS += __shfl_xor(SS, 2);
    S += __shfl_xor(S, 4);  SS += __shfl_xor(SS, 4);
    S += __shfl_xor(S, 8);  SS += __shfl_xor(SS, 8);
    S += __shfl_xor(S, 16); SS += __shfl_xor(SS, 16);
    S += __shfl_xor(S, 32); SS += __shfl_xor(SS, 32);
    if (t == 0) {
        float mu  = S * (1.0f / 8192.0f);
        float var = SS * (1.0f / 8192.0f) - mu * mu;
        float scale = gamma[c] * rsqrtf(var + 1e-5f);
        float shift = beta[c] - mu * scale;
        stats[q * 64 + c] = make_float2(scale, shift);
    }
}

// ---------------------------------------------------------------------------
// Kernel 4: out = (wy * scale + shift) + x, float4-vectorized reassembly.
// ---------------------------------------------------------------------------
__global__ __launch_bounds__(256) void final_kernel(
    const float* __restrict__ wy, const float2* __restrict__ stats,
    const float* __restrict__ x, float* __restrict__ out)
{
    size_t base = ((size_t)blockIdx.x * 256 + threadIdx.x) * 4;
    int n   = (int)(base & 4095);
    int c   = (int)((base >> 12) & 63);
    int blk = (int)(base >> 18);
    int b = blk & 1, q = blk >> 1, qh = q >> 1, qw = q & 1;
    int i = n >> 6, j = n & 63;
    float2 sc = stats[q * 64 + c];
    floatx4 wv = *(const floatx4*)(wy + base);
    size_t xa = ((size_t)(b * 64 + c) * 128 + (qh * 64 + i)) * 128 + qw * 64 + j;
    floatx4 xv = *(const floatx4*)(x + xa);
    floatx4 ov;
#pragma unroll
    for (int k = 0; k < 4; ++k) ov[k] = wv[k] * sc.x + sc.y + xv[k];
    *(floatx4*)(out + xa) = ov;
}

// ---------------------------------------------------------------------------
extern "C" void kernel_launch(void* const* d_in, const int* in_sizes, int n_in,
                              void* d_out, int out_size, void* d_ws, size_t ws_size,
                              hipStream_t stream)
{
    const float* x       = (const float*)d_in[0];
    const float* g_w     = (const float*)d_in[1];
    const float* g_b     = (const float*)d_in[2];
    const float* theta_w = (const float*)d_in[3];
    const float* theta_b = (const float*)d_in[4];
    const float* phi_w   = (const float*)d_in[5];
    const float* phi_b   = (const float*)d_in[6];
    const float* w_w     = (const float*)d_in[7];
    const float* w_b     = (const float*)d_in[8];
    const float* gamma   = (const float*)d_in[9];
    const float* beta    = (const float*)d_in[10];

    char* ws = (char*)d_ws;
    uint16_t* th       = (uint16_t*)(ws);                 // 0 .. 2M
    uint16_t* phT      = (uint16_t*)(ws + (2u << 20));    // 2 .. 4M
    uint16_t* vP       = (uint16_t*)(ws + (4u << 20));    // 4 .. 6M
    float*    wy       = (float*)(ws + (6u << 20));       // 6 .. 14M
    float2*   partials = (float2*)(ws + (14u << 20));     // 128 KB
    float2*   stats    = (float2*)(ws + (14u << 20) + (1u << 18));

    proj_kernel  <<<512,  256, 0, stream>>>(x, theta_w, theta_b, phi_w, phi_b,
                                            g_w, g_b, th, phT, vP);
    flash_kernel <<<256,  512, 0, stream>>>(th, phT, vP, w_w, w_b, wy, partials);
    stats_kernel <<<256,  64,  0, stream>>>(partials, gamma, beta, stats);
    final_kernel <<<2048, 256, 0, stream>>>(wy, stats, x, (float*)d_out);
}

// Round 5
// 123.709 us; speedup vs baseline: 1.1279x; 1.0357x over previous
//
#include <hip/hip_runtime.h>
#include <stdint.h>

typedef __bf16 bf16x8 __attribute__((ext_vector_type(8)));
typedef short  short4v __attribute__((ext_vector_type(4)));   // 4 x bf16 bits
typedef float  floatx4 __attribute__((ext_vector_type(4)));
typedef uint32_t u32x4 __attribute__((ext_vector_type(4)));

#define DI __device__ __forceinline__

// single float -> bf16 bits (compiler-native conversion, RNE)
DI uint16_t bf1(float a) {
    union { __bf16 h; uint16_t u; } r; r.h = (__bf16)a; return r.u;
}

// ---------------------------------------------------------------------------
// Kernel 1: projections via MFMA (unchanged from r10).
// ---------------------------------------------------------------------------
__global__ __launch_bounds__(256) void proj_kernel(
    const float* __restrict__ x,
    const float* __restrict__ tw, const float* __restrict__ tb,
    const float* __restrict__ pw, const float* __restrict__ pb,
    const float* __restrict__ gw, const float* __restrict__ gb,
    uint16_t* __restrict__ th, uint16_t* __restrict__ phT,
    uint16_t* __restrict__ vP)
{
    __shared__ uint16_t ldsg[32 * 68];     // g-output bounce, pad 68 (8B-align ok)
    int nt = blockIdx.x & 63, blk = blockIdx.x >> 6;
    int tid = threadIdx.x, wid = tid >> 6, lane = tid & 63;
    int quad = lane >> 4, low = lane & 15;

    int b = blk & 1, q = blk >> 1, qh = q >> 1, qw = q & 1;
    int pixA = wid * 16 + low;             // pixel within 64-tile (A-row m=low)
    const float* xg = x + (size_t)b * 1048576 +
                      (size_t)(qh * 64 + nt) * 128 + qw * 64 + pixA;

    // A-frags: A0 = ch 0..31, A1 = ch 32..63;  A[m=low][k=quad*8+j]
    float a0[8], a1[8];
#pragma unroll
    for (int j = 0; j < 8; ++j) {
        a0[j] = xg[(size_t)(quad * 8 + j) * 16384];
        a1[j] = xg[(size_t)(32 + quad * 8 + j) * 16384];
    }
    bf16x8 A0, A1;
#pragma unroll
    for (int j = 0; j < 8; ++j) {
        A0[j] = (__bf16)a0[j];
        A1[j] = (__bf16)a1[j];
    }

    // one 16-o output tile: D[m=pixel][n=o0+low] = sum_c x*w + bias
    auto dotile = [&](const float* W, const float* Bv, int o0) -> floatx4 {
        floatx4 acc;
        float bias = Bv[o0 + low];
#pragma unroll
        for (int r = 0; r < 4; ++r) acc[r] = bias;
        const float* wr = W + (o0 + low) * 64 + quad * 8;   // 32B-aligned
        floatx4 w0a = *(const floatx4*)(wr);
        floatx4 w0b = *(const floatx4*)(wr + 4);
        floatx4 w1a = *(const floatx4*)(wr + 32);
        floatx4 w1b = *(const floatx4*)(wr + 36);
        bf16x8 B0, B1;
#pragma unroll
        for (int j = 0; j < 4; ++j) {
            B0[j]     = (__bf16)w0a[j];
            B0[j + 4] = (__bf16)w0b[j];
            B1[j]     = (__bf16)w1a[j];
            B1[j + 4] = (__bf16)w1b[j];
        }
        acc = __builtin_amdgcn_mfma_f32_16x16x32_bf16(A0, B0, acc, 0, 0, 0);
        acc = __builtin_amdgcn_mfma_f32_16x16x32_bf16(A1, B1, acc, 0, 0, 0);
        return acc;
    };

    // D rows: pixel = nt*64 + wid*16 + quad*4 + r; cols: o = o0 + low
    size_t thbase = ((size_t)blk * 4096 + nt * 64 + wid * 16 + quad * 4) * 32;

    floatx4 t0 = dotile(tw, tb, 0), t1 = dotile(tw, tb, 16);
#pragma unroll
    for (int r = 0; r < 4; ++r) {
        th[thbase + r * 32 + low]      = bf1(t0[r] * 1.44269504088896f);
        th[thbase + r * 32 + 16 + low] = bf1(t1[r] * 1.44269504088896f);
    }
    floatx4 p0 = dotile(pw, pb, 0), p1 = dotile(pw, pb, 16);
#pragma unroll
    for (int r = 0; r < 4; ++r) {
        phT[thbase + r * 32 + low]      = bf1(p0[r]);
        phT[thbase + r * 32 + 16 + low] = bf1(p1[r]);
    }
    floatx4 g0 = dotile(gw, gb, 0), g1 = dotile(gw, gb, 16);
#pragma unroll
    for (int r = 0; r < 4; ++r) {
        ldsg[(low)      * 68 + wid * 16 + quad * 4 + r] = bf1(g0[r]);
        ldsg[(16 + low) * 68 + wid * 16 + quad * 4 + r] = bf1(g1[r]);
    }
    __syncthreads();
    // coalesced write-out: thread -> 16B of vP [o=tid>>3][k=(tid&7)*8]
    {
        int o = tid >> 3, k = (tid & 7) * 8;
        const uint16_t* src = &ldsg[o * 68 + k];
        uint64_t lo = *(const uint64_t*)(src);       // 8B-aligned
        uint64_t hi = *(const uint64_t*)(src + 4);
        union { uint64_t q[2]; u32x4 v; } out;
        out.q[0] = lo; out.q[1] = hi;
        *(u32x4*)(vP + (size_t)blk * 131072 + nt * 2048 + tid * 8) = out.v;
    }
}

// ---------------------------------------------------------------------------
// Kernel 2: fused attention + W-projection + BN partial sums.
// r11: split-K x4 with dual-query waves. 8 waves = 4 splits x 2 query-groups;
// wave owns 32 queries over 1024 keys (16 x 64-key tiles, double-buffered).
// Keeps r10's halved per-query LDS traffic (32 q share each K/V fragment)
// while restoring 4 waves/SIMD (grid 512 WGs x 8 waves; LDS 78KB -> 2 WG/CU).
// Inner phase ordered A:QK->softmax->PV then B:... to halve score-register
// liveness (fits 128-VGPR budget) and interleave MFMA/VALU within a wave.
// ---------------------------------------------------------------------------
__global__ __launch_bounds__(512, 4) void flash_kernel(
    const uint16_t* __restrict__ th, const uint16_t* __restrict__ phT,
    const uint16_t* __restrict__ vP, const float* __restrict__ w_w,
    const float* __restrict__ w_b, float* __restrict__ wy,
    float2* __restrict__ partials)
{
    __shared__ uint16_t ldsK[4][2][64 * 40];   // [split][buf] 40 KB
    __shared__ uint16_t ldsV[4][2][32 * 72];   // [split][buf] 36 KB
    __shared__ float sred[2][64][2];           // 1 KB  (total ~78 KB -> 2 WG/CU)
    int blk = blockIdx.x & 7;          // XCD-clustered
    int rg  = blockIdx.x >> 3;         // 0..63
    int tid = threadIdx.x, wid = tid >> 6, lane = tid & 63;
    int sp = wid >> 1, qg = wid & 1;   // split 0..3, query-group 0..1
    int lt = tid & 127;                // thread within split (2 waves)
    int quad = lane >> 4, low = lane & 15;
    int n0 = rg * 64 + qg * 32;        // wave's 32-query base

    const uint16_t* thB = th  + (size_t)blk * 131072;
    const uint16_t* kG  = phT + (size_t)blk * 131072;
    const uint16_t* vG  = vP  + (size_t)blk * 131072;

    bf16x8 qfA = *(const bf16x8*)(thB + (n0 + low) * 32 + quad * 8);
    bf16x8 qfB = *(const bf16x8*)(thB + (n0 + 16 + low) * 32 + quad * 8);

    // split sp stages keys [sp*1024 + t*64, +64); 64-key tile = 256 u32x4,
    // thread item idx = i*128 + lt (i=0,1), fully coalesced.
    const u32x4* kSrc = (const u32x4*)kG + sp * 4096 + lt;
    const u32x4* vSrc = (const u32x4*)vG + sp * 4096 + lt;
    const int kW0 = ((lt >> 2)) * 40 + (lt & 3) * 8;        // rows 0..31
    const int kW1 = (32 + (lt >> 2)) * 40 + (lt & 3) * 8;   // rows 32..63
    const int vW0 = ((lt >> 3)) * 72 + (lt & 7) * 8;        // o 0..15
    const int vW1 = (16 + (lt >> 3)) * 72 + (lt & 7) * 8;   // o 16..31

    u32x4 kr0 = kSrc[0], kr1 = kSrc[128];
    u32x4 vr0 = vSrc[0], vr1 = vSrc[128];
    *(u32x4*)(&ldsK[sp][0][kW0]) = kr0;  *(u32x4*)(&ldsK[sp][0][kW1]) = kr1;
    *(u32x4*)(&ldsV[sp][0][vW0]) = vr0;  *(u32x4*)(&ldsV[sp][0][vW1]) = vr1;
    __syncthreads();

    floatx4 zero = {0.f, 0.f, 0.f, 0.f};
    floatx4 oaA0 = zero, oaA1 = zero, osA = zero;
    floatx4 oaB0 = zero, oaB1 = zero, osB = zero;
    union { uint32_t u[2]; short4v v; } ones;
    ones.u[0] = 0x3F803F80u; ones.u[1] = 0x3F803F80u;

    for (int t = 0; t < 16; ++t) {
        int buf = t & 1;
        if (t < 15) {
            kr0 = kSrc[(t + 1) * 256];  kr1 = kSrc[(t + 1) * 256 + 128];
            vr0 = vSrc[(t + 1) * 256];  vr1 = vSrc[(t + 1) * 256 + 128];
        }
        const uint16_t* Kb = ldsK[sp][buf];
        const uint16_t* Vb = ldsV[sp][buf];
        bf16x8  kf[4]; short4v va[4], vb[4];
#pragma unroll
        for (int c = 0; c < 4; ++c) {
            kf[c] = *(const bf16x8*)(Kb + (c * 16 + low) * 40 + quad * 8);
            va[c] = *(const short4v*)(Vb + low * 72 + c * 16 + quad * 4);
            vb[c] = *(const short4v*)(Vb + (16 + low) * 72 + c * 16 + quad * 4);
        }
        // ---- group A ----
        {
            floatx4 sa[4];
#pragma unroll
            for (int c = 0; c < 4; ++c)
                sa[c] = __builtin_amdgcn_mfma_f32_16x16x32_bf16(kf[c], qfA, zero, 0, 0, 0);
            union { __bf16 h[4]; short4v v; } P[4];
#pragma unroll
            for (int c = 0; c < 4; ++c) {
                P[c].h[0] = (__bf16)__builtin_amdgcn_exp2f(sa[c][0]);
                P[c].h[1] = (__bf16)__builtin_amdgcn_exp2f(sa[c][1]);
                P[c].h[2] = (__bf16)__builtin_amdgcn_exp2f(sa[c][2]);
                P[c].h[3] = (__bf16)__builtin_amdgcn_exp2f(sa[c][3]);
            }
#pragma unroll
            for (int c = 0; c < 4; ++c) {
                oaA0 = __builtin_amdgcn_mfma_f32_16x16x16bf16_1k(va[c], P[c].v, oaA0, 0, 0, 0);
                oaA1 = __builtin_amdgcn_mfma_f32_16x16x16bf16_1k(vb[c], P[c].v, oaA1, 0, 0, 0);
                osA  = __builtin_amdgcn_mfma_f32_16x16x16bf16_1k(ones.v, P[c].v, osA, 0, 0, 0);
            }
        }
        // ---- group B ----
        {
            floatx4 sa[4];
#pragma unroll
            for (int c = 0; c < 4; ++c)
                sa[c] = __builtin_amdgcn_mfma_f32_16x16x32_bf16(kf[c], qfB, zero, 0, 0, 0);
            union { __bf16 h[4]; short4v v; } P[4];
#pragma unroll
            for (int c = 0; c < 4; ++c) {
                P[c].h[0] = (__bf16)__builtin_amdgcn_exp2f(sa[c][0]);
                P[c].h[1] = (__bf16)__builtin_amdgcn_exp2f(sa[c][1]);
                P[c].h[2] = (__bf16)__builtin_amdgcn_exp2f(sa[c][2]);
                P[c].h[3] = (__bf16)__builtin_amdgcn_exp2f(sa[c][3]);
            }
#pragma unroll
            for (int c = 0; c < 4; ++c) {
                oaB0 = __builtin_amdgcn_mfma_f32_16x16x16bf16_1k(va[c], P[c].v, oaB0, 0, 0, 0);
                oaB1 = __builtin_amdgcn_mfma_f32_16x16x16bf16_1k(vb[c], P[c].v, oaB1, 0, 0, 0);
                osB  = __builtin_amdgcn_mfma_f32_16x16x16bf16_1k(ones.v, P[c].v, osB, 0, 0, 0);
            }
        }
        if (t < 15) {
            *(u32x4*)(&ldsK[sp][buf ^ 1][kW0]) = kr0;
            *(u32x4*)(&ldsK[sp][buf ^ 1][kW1]) = kr1;
            *(u32x4*)(&ldsV[sp][buf ^ 1][vW0]) = vr0;
            *(u32x4*)(&ldsV[sp][buf ^ 1][vW1]) = vr1;
        }
        __syncthreads();
    }

    // ---- cross-split combine: 18 floats/thread via reused K-LDS ----
    {
        float* exW = (float*)(&ldsK[0][0][0]);   // 512*18*4B = 36864B <= 40960B
        int li = tid * 18;
#pragma unroll
        for (int r = 0; r < 4; ++r) {
            exW[li + r]      = oaA0[r];
            exW[li + 4 + r]  = oaA1[r];
            exW[li + 9 + r]  = oaB0[r];
            exW[li + 13 + r] = oaB1[r];
        }
        exW[li + 8]  = osA[0];
        exW[li + 17] = osB[0];
    }
    __syncthreads();
    floatx4 cA0 = zero, cA1 = zero, cB0 = zero, cB1 = zero;
    float cosA = 0.f, cosB = 0.f;
    {
        const float* exR = (const float*)(&ldsK[0][0][0]);
#pragma unroll
        for (int s = 0; s < 4; ++s) {
            const float* p = exR + (s * 128 + lt) * 18;
#pragma unroll
            for (int r = 0; r < 4; ++r) {
                cA0[r] += p[r];
                cA1[r] += p[4 + r];
                cB0[r] += p[9 + r];
                cB1[r] += p[13 + r];
            }
            cosA += p[8];
            cosB += p[17];
        }
    }

    // ---- epilogue: normalize, W-projection via MFMA, BN partials ----
    // each split does 1 of the 4 ct tiles (channels [sp*16, sp*16+16))
    float rinvA = 1.0f / cosA, rinvB = 1.0f / cosB;
    union { __bf16 h[4]; short4v v; } YA0, YA1, YB0, YB1;
#pragma unroll
    for (int r = 0; r < 4; ++r) {
        YA0.h[r] = (__bf16)(cA0[r] * rinvA);
        YA1.h[r] = (__bf16)(cA1[r] * rinvA);
        YB0.h[r] = (__bf16)(cB0[r] * rinvB);
        YB1.h[r] = (__bf16)(cB1[r] * rinvB);
    }

    float* wyB = wy + (size_t)blk * 262144;
    int nA = n0 + low, nB = n0 + 16 + low;
    int ct = sp;
    {
        floatx4 accA, accB;
#pragma unroll
        for (int r = 0; r < 4; ++r) {
            accA[r] = w_b[ct * 16 + quad * 4 + r];
            accB[r] = accA[r];
        }
        floatx4 w0 = *(const floatx4*)(w_w + (ct * 16 + low) * 32 + quad * 4);
        floatx4 w1 = *(const floatx4*)(w_w + (ct * 16 + low) * 32 + 16 + quad * 4);
        union { __bf16 h[4]; short4v v; } W0, W1;
#pragma unroll
        for (int r = 0; r < 4; ++r) {
            W0.h[r] = (__bf16)w0[r];
            W1.h[r] = (__bf16)w1[r];
        }
        accA = __builtin_amdgcn_mfma_f32_16x16x16bf16_1k(W0.v, YA0.v, accA, 0, 0, 0);
        accA = __builtin_amdgcn_mfma_f32_16x16x16bf16_1k(W1.v, YA1.v, accA, 0, 0, 0);
        accB = __builtin_amdgcn_mfma_f32_16x16x16bf16_1k(W0.v, YB0.v, accB, 0, 0, 0);
        accB = __builtin_amdgcn_mfma_f32_16x16x16bf16_1k(W1.v, YB1.v, accB, 0, 0, 0);
#pragma unroll
        for (int r = 0; r < 4; ++r) {
            int ch = ct * 16 + quad * 4 + r;
            wyB[(size_t)ch * 4096 + nA] = accA[r];
            wyB[(size_t)ch * 4096 + nB] = accB[r];
            float s = accA[r] + accB[r];
            float ss = accA[r] * accA[r] + accB[r] * accB[r];
            s += __shfl_xor(s, 1); ss += __shfl_xor(ss, 1);
            s += __shfl_xor(s, 2); ss += __shfl_xor(ss, 2);
            s += __shfl_xor(s, 4); ss += __shfl_xor(ss, 4);
            s += __shfl_xor(s, 8); ss += __shfl_xor(ss, 8);
            if (low == 0) {
                sred[qg][ch][0] = s;
                sred[qg][ch][1] = ss;
            }
        }
    }
    __syncthreads();
    if (tid < 64) {
        float s  = sred[0][tid][0] + sred[1][tid][0];
        float ss = sred[0][tid][1] + sred[1][tid][1];
        partials[((size_t)blk * 64 + rg) * 64 + tid] = make_float2(s, ss);
    }
}

// ---------------------------------------------------------------------------
// Kernel 3: BN stats — grid 256 = (q<<6)|c, block 64 (one thread per rg).
// Each thread sums its rg over both batches, then 64-lane shuffle reduce.
// ---------------------------------------------------------------------------
__global__ __launch_bounds__(64) void stats_kernel(
    const float2* __restrict__ partials, const float* __restrict__ gamma,
    const float* __restrict__ beta, float2* __restrict__ stats)
{
    int q = blockIdx.x >> 6, c = blockIdx.x & 63;
    int t = threadIdx.x;                       // rg
    float2 p0 = partials[(((size_t)(q * 2 + 0)) * 64 + t) * 64 + c];
    float2 p1 = partials[(((size_t)(q * 2 + 1)) * 64 + t) * 64 + c];
    float S = p0.x + p1.x, SS = p0.y + p1.y;
    S += __shfl_xor(S, 1);  SS += __shfl_xor(SS, 1);
    S += __shfl_xor(S, 2);  SS += __shfl_xor(SS, 2);
    S += __shfl_xor(S, 4);  SS += __shfl_xor(SS, 4);
    S += __shfl_xor(S, 8);  SS += __shfl_xor(SS, 8);
    S += __shfl_xor(S, 16); SS += __shfl_xor(SS, 16);
    S += __shfl_xor(S, 32); SS += __shfl_xor(SS, 32);
    if (t == 0) {
        float mu  = S * (1.0f / 8192.0f);
        float var = SS * (1.0f / 8192.0f) - mu * mu;
        float scale = gamma[c] * rsqrtf(var + 1e-5f);
        float shift = beta[c] - mu * scale;
        stats[q * 64 + c] = make_float2(scale, shift);
    }
}

// ---------------------------------------------------------------------------
// Kernel 4: out = (wy * scale + shift) + x, float4-vectorized reassembly.
// ---------------------------------------------------------------------------
__global__ __launch_bounds__(256) void final_kernel(
    const float* __restrict__ wy, const float2* __restrict__ stats,
    const float* __restrict__ x, float* __restrict__ out)
{
    size_t base = ((size_t)blockIdx.x * 256 + threadIdx.x) * 4;
    int n   = (int)(base & 4095);
    int c   = (int)((base >> 12) & 63);
    int blk = (int)(base >> 18);
    int b = blk & 1, q = blk >> 1, qh = q >> 1, qw = q & 1;
    int i = n >> 6, j = n & 63;
    float2 sc = stats[q * 64 + c];
    floatx4 wv = *(const floatx4*)(wy + base);
    size_t xa = ((size_t)(b * 64 + c) * 128 + (qh * 64 + i)) * 128 + qw * 64 + j;
    floatx4 xv = *(const floatx4*)(x + xa);
    floatx4 ov;
#pragma unroll
    for (int k = 0; k < 4; ++k) ov[k] = wv[k] * sc.x + sc.y + xv[k];
    *(floatx4*)(out + xa) = ov;
}

// ---------------------------------------------------------------------------
extern "C" void kernel_launch(void* const* d_in, const int* in_sizes, int n_in,
                              void* d_out, int out_size, void* d_ws, size_t ws_size,
                              hipStream_t stream)
{
    const float* x       = (const float*)d_in[0];
    const float* g_w     = (const float*)d_in[1];
    const float* g_b     = (const float*)d_in[2];
    const float* theta_w = (const float*)d_in[3];
    const float* theta_b = (const float*)d_in[4];
    const float* phi_w   = (const float*)d_in[5];
    const float* phi_b   = (const float*)d_in[6];
    const float* w_w     = (const float*)d_in[7];
    const float* w_b     = (const float*)d_in[8];
    const float* gamma   = (const float*)d_in[9];
    const float* beta    = (const float*)d_in[10];

    char* ws = (char*)d_ws;
    uint16_t* th       = (uint16_t*)(ws);                 // 0 .. 2M
    uint16_t* phT      = (uint16_t*)(ws + (2u << 20));    // 2 .. 4M
    uint16_t* vP       = (uint16_t*)(ws + (4u << 20));    // 4 .. 6M
    float*    wy       = (float*)(ws + (6u << 20));       // 6 .. 14M
    float2*   partials = (float2*)(ws + (14u << 20));     // 256 KB
    float2*   stats    = (float2*)(ws + (14u << 20) + (1u << 18));

    proj_kernel  <<<512,  256, 0, stream>>>(x, theta_w, theta_b, phi_w, phi_b,
                                            g_w, g_b, th, phT, vP);
    flash_kernel <<<512,  512, 0, stream>>>(th, phT, vP, w_w, w_b, wy, partials);
    stats_kernel <<<256,  64,  0, stream>>>(partials, gamma, beta, stats);
    final_kernel <<<2048, 256, 0, stream>>>(wy, stats, x, (float*)d_out);
}

// Round 6
// 123.268 us; speedup vs baseline: 1.1320x; 1.0036x over previous
//
#include <hip/hip_runtime.h>
#include <stdint.h>

typedef __bf16 bf16x8 __attribute__((ext_vector_type(8)));
typedef short  short4v __attribute__((ext_vector_type(4)));   // 4 x bf16 bits
typedef float  floatx4 __attribute__((ext_vector_type(4)));
typedef uint32_t u32x4 __attribute__((ext_vector_type(4)));

#define DI __device__ __forceinline__

// single float -> bf16 bits (compiler-native conversion, RNE)
DI uint16_t bf1(float a) {
    union { __bf16 h; uint16_t u; } r; r.h = (__bf16)a; return r.u;
}

// ---------------------------------------------------------------------------
// Kernel 1: projections via MFMA. r12: XCD-clustered blk (bid & 7) so each
// quadrant's th/phT/vP outputs are produced on the XCD that flash consumes
// them from (flash uses the same mapping).
// ---------------------------------------------------------------------------
__global__ __launch_bounds__(256) void proj_kernel(
    const float* __restrict__ x,
    const float* __restrict__ tw, const float* __restrict__ tb,
    const float* __restrict__ pw, const float* __restrict__ pb,
    const float* __restrict__ gw, const float* __restrict__ gb,
    uint16_t* __restrict__ th, uint16_t* __restrict__ phT,
    uint16_t* __restrict__ vP)
{
    __shared__ uint16_t ldsg[32 * 68];     // g-output bounce, pad 68 (8B-align ok)
    int blk = blockIdx.x & 7, nt = blockIdx.x >> 3;
    int tid = threadIdx.x, wid = tid >> 6, lane = tid & 63;
    int quad = lane >> 4, low = lane & 15;

    int b = blk & 1, q = blk >> 1, qh = q >> 1, qw = q & 1;
    int pixA = wid * 16 + low;             // pixel within 64-tile (A-row m=low)
    const float* xg = x + (size_t)b * 1048576 +
                      (size_t)(qh * 64 + nt) * 128 + qw * 64 + pixA;

    // A-frags: A0 = ch 0..31, A1 = ch 32..63;  A[m=low][k=quad*8+j]
    float a0[8], a1[8];
#pragma unroll
    for (int j = 0; j < 8; ++j) {
        a0[j] = xg[(size_t)(quad * 8 + j) * 16384];
        a1[j] = xg[(size_t)(32 + quad * 8 + j) * 16384];
    }
    bf16x8 A0, A1;
#pragma unroll
    for (int j = 0; j < 8; ++j) {
        A0[j] = (__bf16)a0[j];
        A1[j] = (__bf16)a1[j];
    }

    // one 16-o output tile: D[m=pixel][n=o0+low] = sum_c x*w + bias
    auto dotile = [&](const float* W, const float* Bv, int o0) -> floatx4 {
        floatx4 acc;
        float bias = Bv[o0 + low];
#pragma unroll
        for (int r = 0; r < 4; ++r) acc[r] = bias;
        const float* wr = W + (o0 + low) * 64 + quad * 8;   // 32B-aligned
        floatx4 w0a = *(const floatx4*)(wr);
        floatx4 w0b = *(const floatx4*)(wr + 4);
        floatx4 w1a = *(const floatx4*)(wr + 32);
        floatx4 w1b = *(const floatx4*)(wr + 36);
        bf16x8 B0, B1;
#pragma unroll
        for (int j = 0; j < 4; ++j) {
            B0[j]     = (__bf16)w0a[j];
            B0[j + 4] = (__bf16)w0b[j];
            B1[j]     = (__bf16)w1a[j];
            B1[j + 4] = (__bf16)w1b[j];
        }
        acc = __builtin_amdgcn_mfma_f32_16x16x32_bf16(A0, B0, acc, 0, 0, 0);
        acc = __builtin_amdgcn_mfma_f32_16x16x32_bf16(A1, B1, acc, 0, 0, 0);
        return acc;
    };

    // D rows: pixel = nt*64 + wid*16 + quad*4 + r; cols: o = o0 + low
    size_t thbase = ((size_t)blk * 4096 + nt * 64 + wid * 16 + quad * 4) * 32;

    floatx4 t0 = dotile(tw, tb, 0), t1 = dotile(tw, tb, 16);
#pragma unroll
    for (int r = 0; r < 4; ++r) {
        th[thbase + r * 32 + low]      = bf1(t0[r] * 1.44269504088896f);
        th[thbase + r * 32 + 16 + low] = bf1(t1[r] * 1.44269504088896f);
    }
    floatx4 p0 = dotile(pw, pb, 0), p1 = dotile(pw, pb, 16);
#pragma unroll
    for (int r = 0; r < 4; ++r) {
        phT[thbase + r * 32 + low]      = bf1(p0[r]);
        phT[thbase + r * 32 + 16 + low] = bf1(p1[r]);
    }
    floatx4 g0 = dotile(gw, gb, 0), g1 = dotile(gw, gb, 16);
#pragma unroll
    for (int r = 0; r < 4; ++r) {
        ldsg[(low)      * 68 + wid * 16 + quad * 4 + r] = bf1(g0[r]);
        ldsg[(16 + low) * 68 + wid * 16 + quad * 4 + r] = bf1(g1[r]);
    }
    __syncthreads();
    // coalesced write-out: thread -> 16B of vP [o=tid>>3][k=(tid&7)*8]
    {
        int o = tid >> 3, k = (tid & 7) * 8;
        const uint16_t* src = &ldsg[o * 68 + k];
        uint64_t lo = *(const uint64_t*)(src);       // 8B-aligned
        uint64_t hi = *(const uint64_t*)(src + 4);
        union { uint64_t q[2]; u32x4 v; } out;
        out.q[0] = lo; out.q[1] = hi;
        *(u32x4*)(vP + (size_t)blk * 131072 + nt * 2048 + tid * 8) = out.v;
    }
}

// ---------------------------------------------------------------------------
// Kernel 2: fused attention + W-projection + BN partial sums.
// r12 over r11 (split-K x4 dual-query structure kept):
//  PV/os/epilogue MFMAs widened to 16x16x32 by concatenating adjacent K=16
//  fragments: B-slot k=quad*8+j maps to key c2*32+16*(j>>2)+quad*4+(j&3),
//  which is exactly P[2c2] ll P[2c2+1]; the matching A operand is
//  va[2c2] ll va[2c2+1] (registers we already hold). MFMA instrs/iter 32->20.
// ---------------------------------------------------------------------------
__global__ __launch_bounds__(512, 4) void flash_kernel(
    const uint16_t* __restrict__ th, const uint16_t* __restrict__ phT,
    const uint16_t* __restrict__ vP, const float* __restrict__ w_w,
    const float* __restrict__ w_b, float* __restrict__ wy,
    float2* __restrict__ partials)
{
    __shared__ uint16_t ldsK[4][2][64 * 40];   // [split][buf] 40 KB
    __shared__ uint16_t ldsV[4][2][32 * 72];   // [split][buf] 36 KB
    __shared__ float sred[2][64][2];           // 1 KB  (total ~78 KB -> 2 WG/CU)
    int blk = blockIdx.x & 7;          // XCD-clustered
    int rg  = blockIdx.x >> 3;         // 0..63
    int tid = threadIdx.x, wid = tid >> 6, lane = tid & 63;
    int sp = wid >> 1, qg = wid & 1;   // split 0..3, query-group 0..1
    int lt = tid & 127;                // thread within split (2 waves)
    int quad = lane >> 4, low = lane & 15;
    int n0 = rg * 64 + qg * 32;        // wave's 32-query base

    const uint16_t* thB = th  + (size_t)blk * 131072;
    const uint16_t* kG  = phT + (size_t)blk * 131072;
    const uint16_t* vG  = vP  + (size_t)blk * 131072;

    bf16x8 qfA = *(const bf16x8*)(thB + (n0 + low) * 32 + quad * 8);
    bf16x8 qfB = *(const bf16x8*)(thB + (n0 + 16 + low) * 32 + quad * 8);

    // split sp stages keys [sp*1024 + t*64, +64); 64-key tile = 256 u32x4,
    // thread item idx = i*128 + lt (i=0,1), fully coalesced.
    const u32x4* kSrc = (const u32x4*)kG + sp * 4096 + lt;
    const u32x4* vSrc = (const u32x4*)vG + sp * 4096 + lt;
    const int kW0 = ((lt >> 2)) * 40 + (lt & 3) * 8;        // rows 0..31
    const int kW1 = (32 + (lt >> 2)) * 40 + (lt & 3) * 8;   // rows 32..63
    const int vW0 = ((lt >> 3)) * 72 + (lt & 7) * 8;        // o 0..15
    const int vW1 = (16 + (lt >> 3)) * 72 + (lt & 7) * 8;   // o 16..31

    u32x4 kr0 = kSrc[0], kr1 = kSrc[128];
    u32x4 vr0 = vSrc[0], vr1 = vSrc[128];
    *(u32x4*)(&ldsK[sp][0][kW0]) = kr0;  *(u32x4*)(&ldsK[sp][0][kW1]) = kr1;
    *(u32x4*)(&ldsV[sp][0][vW0]) = vr0;  *(u32x4*)(&ldsV[sp][0][vW1]) = vr1;
    __syncthreads();

    floatx4 zero = {0.f, 0.f, 0.f, 0.f};
    floatx4 oaA0 = zero, oaA1 = zero, osA = zero;
    floatx4 oaB0 = zero, oaB1 = zero, osB = zero;
    union { uint32_t u[4]; bf16x8 v; } ones8;
    ones8.u[0] = 0x3F803F80u; ones8.u[1] = 0x3F803F80u;
    ones8.u[2] = 0x3F803F80u; ones8.u[3] = 0x3F803F80u;

    for (int t = 0; t < 16; ++t) {
        int buf = t & 1;
        if (t < 15) {
            kr0 = kSrc[(t + 1) * 256];  kr1 = kSrc[(t + 1) * 256 + 128];
            vr0 = vSrc[(t + 1) * 256];  vr1 = vSrc[(t + 1) * 256 + 128];
        }
        const uint16_t* Kb = ldsK[sp][buf];
        const uint16_t* Vb = ldsV[sp][buf];
        bf16x8 kf[4];
        union { short4v s[2]; bf16x8 v; } vA2[2], vB2[2];
#pragma unroll
        for (int c = 0; c < 4; ++c)
            kf[c] = *(const bf16x8*)(Kb + (c * 16 + low) * 40 + quad * 8);
#pragma unroll
        for (int c2 = 0; c2 < 2; ++c2) {
            vA2[c2].s[0] = *(const short4v*)(Vb + low * 72 + (2*c2)     * 16 + quad * 4);
            vA2[c2].s[1] = *(const short4v*)(Vb + low * 72 + (2*c2 + 1) * 16 + quad * 4);
            vB2[c2].s[0] = *(const short4v*)(Vb + (16 + low) * 72 + (2*c2)     * 16 + quad * 4);
            vB2[c2].s[1] = *(const short4v*)(Vb + (16 + low) * 72 + (2*c2 + 1) * 16 + quad * 4);
        }
        // ---- group A ----
        {
            floatx4 sa[4];
#pragma unroll
            for (int c = 0; c < 4; ++c)
                sa[c] = __builtin_amdgcn_mfma_f32_16x16x32_bf16(kf[c], qfA, zero, 0, 0, 0);
            union { __bf16 h[8]; bf16x8 v; } P2[2];
#pragma unroll
            for (int c2 = 0; c2 < 2; ++c2) {
#pragma unroll
                for (int j = 0; j < 4; ++j) {
                    P2[c2].h[j]     = (__bf16)__builtin_amdgcn_exp2f(sa[2*c2][j]);
                    P2[c2].h[4 + j] = (__bf16)__builtin_amdgcn_exp2f(sa[2*c2 + 1][j]);
                }
            }
#pragma unroll
            for (int c2 = 0; c2 < 2; ++c2) {
                oaA0 = __builtin_amdgcn_mfma_f32_16x16x32_bf16(vA2[c2].v, P2[c2].v, oaA0, 0, 0, 0);
                oaA1 = __builtin_amdgcn_mfma_f32_16x16x32_bf16(vB2[c2].v, P2[c2].v, oaA1, 0, 0, 0);
                osA  = __builtin_amdgcn_mfma_f32_16x16x32_bf16(ones8.v,   P2[c2].v, osA,  0, 0, 0);
            }
        }
        // ---- group B ----
        {
            floatx4 sa[4];
#pragma unroll
            for (int c = 0; c < 4; ++c)
                sa[c] = __builtin_amdgcn_mfma_f32_16x16x32_bf16(kf[c], qfB, zero, 0, 0, 0);
            union { __bf16 h[8]; bf16x8 v; } P2[2];
#pragma unroll
            for (int c2 = 0; c2 < 2; ++c2) {
#pragma unroll
                for (int j = 0; j < 4; ++j) {
                    P2[c2].h[j]     = (__bf16)__builtin_amdgcn_exp2f(sa[2*c2][j]);
                    P2[c2].h[4 + j] = (__bf16)__builtin_amdgcn_exp2f(sa[2*c2 + 1][j]);
                }
            }
#pragma unroll
            for (int c2 = 0; c2 < 2; ++c2) {
                oaB0 = __builtin_amdgcn_mfma_f32_16x16x32_bf16(vA2[c2].v, P2[c2].v, oaB0, 0, 0, 0);
                oaB1 = __builtin_amdgcn_mfma_f32_16x16x32_bf16(vB2[c2].v, P2[c2].v, oaB1, 0, 0, 0);
                osB  = __builtin_amdgcn_mfma_f32_16x16x32_bf16(ones8.v,   P2[c2].v, osB,  0, 0, 0);
            }
        }
        if (t < 15) {
            *(u32x4*)(&ldsK[sp][buf ^ 1][kW0]) = kr0;
            *(u32x4*)(&ldsK[sp][buf ^ 1][kW1]) = kr1;
            *(u32x4*)(&ldsV[sp][buf ^ 1][vW0]) = vr0;
            *(u32x4*)(&ldsV[sp][buf ^ 1][vW1]) = vr1;
        }
        __syncthreads();
    }

    // ---- cross-split combine: 18 floats/thread via reused K-LDS ----
    {
        float* exW = (float*)(&ldsK[0][0][0]);   // 512*18*4B = 36864B <= 40960B
        int li = tid * 18;
#pragma unroll
        for (int r = 0; r < 4; ++r) {
            exW[li + r]      = oaA0[r];
            exW[li + 4 + r]  = oaA1[r];
            exW[li + 9 + r]  = oaB0[r];
            exW[li + 13 + r] = oaB1[r];
        }
        exW[li + 8]  = osA[0];
        exW[li + 17] = osB[0];
    }
    __syncthreads();
    floatx4 cA0 = zero, cA1 = zero, cB0 = zero, cB1 = zero;
    float cosA = 0.f, cosB = 0.f;
    {
        const float* exR = (const float*)(&ldsK[0][0][0]);
#pragma unroll
        for (int s = 0; s < 4; ++s) {
            const float* p = exR + (s * 128 + lt) * 18;
#pragma unroll
            for (int r = 0; r < 4; ++r) {
                cA0[r] += p[r];
                cA1[r] += p[4 + r];
                cB0[r] += p[9 + r];
                cB1[r] += p[13 + r];
            }
            cosA += p[8];
            cosB += p[17];
        }
    }

    // ---- epilogue: normalize, W-projection via one 16x16x32 MFMA each ----
    float rinvA = 1.0f / cosA, rinvB = 1.0f / cosB;
    union { __bf16 h[8]; bf16x8 v; } YA8, YB8;
#pragma unroll
    for (int r = 0; r < 4; ++r) {
        YA8.h[r]     = (__bf16)(cA0[r] * rinvA);
        YA8.h[4 + r] = (__bf16)(cA1[r] * rinvA);
        YB8.h[r]     = (__bf16)(cB0[r] * rinvB);
        YB8.h[4 + r] = (__bf16)(cB1[r] * rinvB);
    }

    float* wyB = wy + (size_t)blk * 262144;
    int nA = n0 + low, nB = n0 + 16 + low;
    int ct = sp;
    {
        floatx4 accA, accB;
#pragma unroll
        for (int r = 0; r < 4; ++r) {
            accA[r] = w_b[ct * 16 + quad * 4 + r];
            accB[r] = accA[r];
        }
        floatx4 w0 = *(const floatx4*)(w_w + (ct * 16 + low) * 32 + quad * 4);
        floatx4 w1 = *(const floatx4*)(w_w + (ct * 16 + low) * 32 + 16 + quad * 4);
        union { __bf16 h[8]; bf16x8 v; } W8;
#pragma unroll
        for (int r = 0; r < 4; ++r) {
            W8.h[r]     = (__bf16)w0[r];
            W8.h[4 + r] = (__bf16)w1[r];
        }
        accA = __builtin_amdgcn_mfma_f32_16x16x32_bf16(W8.v, YA8.v, accA, 0, 0, 0);
        accB = __builtin_amdgcn_mfma_f32_16x16x32_bf16(W8.v, YB8.v, accB, 0, 0, 0);
#pragma unroll
        for (int r = 0; r < 4; ++r) {
            int ch = ct * 16 + quad * 4 + r;
            wyB[(size_t)ch * 4096 + nA] = accA[r];
            wyB[(size_t)ch * 4096 + nB] = accB[r];
            float s = accA[r] + accB[r];
            float ss = accA[r] * accA[r] + accB[r] * accB[r];
            s += __shfl_xor(s, 1); ss += __shfl_xor(ss, 1);
            s += __shfl_xor(s, 2); ss += __shfl_xor(ss, 2);
            s += __shfl_xor(s, 4); ss += __shfl_xor(ss, 4);
            s += __shfl_xor(s, 8); ss += __shfl_xor(ss, 8);
            if (low == 0) {
                sred[qg][ch][0] = s;
                sred[qg][ch][1] = ss;
            }
        }
    }
    __syncthreads();
    if (tid < 64) {
        float s  = sred[0][tid][0] + sred[1][tid][0];
        float ss = sred[0][tid][1] + sred[1][tid][1];
        partials[((size_t)blk * 64 + rg) * 64 + tid] = make_float2(s, ss);
    }
}

// ---------------------------------------------------------------------------
// Kernel 3: BN stats — grid 256 = (q<<6)|c, block 64 (one thread per rg).
// ---------------------------------------------------------------------------
__global__ __launch_bounds__(64) void stats_kernel(
    const float2* __restrict__ partials, const float* __restrict__ gamma,
    const float* __restrict__ beta, float2* __restrict__ stats)
{
    int q = blockIdx.x >> 6, c = blockIdx.x & 63;
    int t = threadIdx.x;                       // rg
    float2 p0 = partials[(((size_t)(q * 2 + 0)) * 64 + t) * 64 + c];
    float2 p1 = partials[(((size_t)(q * 2 + 1)) * 64 + t) * 64 + c];
    float S = p0.x + p1.x, SS = p0.y + p1.y;
    S += __shfl_xor(S, 1);  SS += __shfl_xor(SS, 1);
    S += __shfl_xor(S, 2);  SS += __shfl_xor(SS, 2);
    S += __shfl_xor(S, 4);  SS += __shfl_xor(SS, 4);
    S += __shfl_xor(S, 8);  SS += __shfl_xor(SS, 8);
    S += __shfl_xor(S, 16); SS += __shfl_xor(SS, 16);
    S += __shfl_xor(S, 32); SS += __shfl_xor(SS, 32);
    if (t == 0) {
        float mu  = S * (1.0f / 8192.0f);
        float var = SS * (1.0f / 8192.0f) - mu * mu;
        float scale = gamma[c] * rsqrtf(var + 1e-5f);
        float shift = beta[c] - mu * scale;
        stats[q * 64 + c] = make_float2(scale, shift);
    }
}

// ---------------------------------------------------------------------------
// Kernel 4: out = (wy * scale + shift) + x. r12: XCD-clustered (bid & 7 =
// blk) so the 16MB wy read hits the L2 of the XCD that produced it.
// ---------------------------------------------------------------------------
__global__ __launch_bounds__(256) void final_kernel(
    const float* __restrict__ wy, const float2* __restrict__ stats,
    const float* __restrict__ x, float* __restrict__ out)
{
    int bid = blockIdx.x;
    size_t base = (((size_t)(bid & 7) * 256 + (bid >> 3)) * 256 + threadIdx.x) * 4;
    int n   = (int)(base & 4095);
    int c   = (int)((base >> 12) & 63);
    int blk = (int)(base >> 18);
    int b = blk & 1, q = blk >> 1, qh = q >> 1, qw = q & 1;
    int i = n >> 6, j = n & 63;
    float2 sc = stats[q * 64 + c];
    floatx4 wv = *(const floatx4*)(wy + base);
    size_t xa = ((size_t)(b * 64 + c) * 128 + (qh * 64 + i)) * 128 + qw * 64 + j;
    floatx4 xv = *(const floatx4*)(x + xa);
    floatx4 ov;
#pragma unroll
    for (int k = 0; k < 4; ++k) ov[k] = wv[k] * sc.x + sc.y + xv[k];
    *(floatx4*)(out + xa) = ov;
}

// ---------------------------------------------------------------------------
extern "C" void kernel_launch(void* const* d_in, const int* in_sizes, int n_in,
                              void* d_out, int out_size, void* d_ws, size_t ws_size,
                              hipStream_t stream)
{
    const float* x       = (const float*)d_in[0];
    const float* g_w     = (const float*)d_in[1];
    const float* g_b     = (const float*)d_in[2];
    const float* theta_w = (const float*)d_in[3];
    const float* theta_b = (const float*)d_in[4];
    const float* phi_w   = (const float*)d_in[5];
    const float* phi_b   = (const float*)d_in[6];
    const float* w_w     = (const float*)d_in[7];
    const float* w_b     = (const float*)d_in[8];
    const float* gamma   = (const float*)d_in[9];
    const float* beta    = (const float*)d_in[10];

    char* ws = (char*)d_ws;
    uint16_t* th       = (uint16_t*)(ws);                 // 0 .. 2M
    uint16_t* phT      = (uint16_t*)(ws + (2u << 20));    // 2 .. 4M
    uint16_t* vP       = (uint16_t*)(ws + (4u << 20));    // 4 .. 6M
    float*    wy       = (float*)(ws + (6u << 20));       // 6 .. 14M
    float2*   partials = (float2*)(ws + (14u << 20));     // 256 KB
    float2*   stats    = (float2*)(ws + (14u << 20) + (1u << 18));

    proj_kernel  <<<512,  256, 0, stream>>>(x, theta_w, theta_b, phi_w, phi_b,
                                            g_w, g_b, th, phT, vP);
    flash_kernel <<<512,  512, 0, stream>>>(th, phT, vP, w_w, w_b, wy, partials);
    stats_kernel <<<256,  64,  0, stream>>>(partials, gamma, beta, stats);
    final_kernel <<<2048, 256, 0, stream>>>(wy, stats, x, (float*)d_out);
}